// Round 1
// baseline (93.803 us; speedup 1.0000x reference)
//
#include <hip/hip_runtime.h>

// TemplatePointwiseAttention on MI355X (gfx950).
// T=4 templates, R=384, d_t=64, d_z=128, H=4 heads, D=16.
// All GEMMs computed transposed (C = W^T * X^T) with pixels on the MFMA
// column axis so per-head d-slices are lane-local; softmax over T=4 is
// un-shifted (logits are O(5)) so K and V share one pass over t.

typedef __bf16 bf16x8 __attribute__((ext_vector_type(8)));
typedef float f32x4 __attribute__((ext_vector_type(4)));
typedef unsigned int u32x4 __attribute__((ext_vector_type(4)));
typedef unsigned int u32x2 __attribute__((ext_vector_type(2)));

#define MFMA16(A, B, C) __builtin_amdgcn_mfma_f32_16x16x32_bf16((A), (B), (C), 0, 0, 0)

// RNE f32->bf16, packed pair (a -> low16, b -> high16)
__device__ __forceinline__ unsigned int f2b_pk(float a, float b) {
  unsigned int ua = __float_as_uint(a), ub = __float_as_uint(b);
  ua = (ua + 0x7fffu + ((ua >> 16) & 1u)) >> 16;
  ub = (ub + 0x7fffu + ((ub >> 16) & 1u)) & 0xffff0000u;
  return ua | ub;
}

// load 8 contiguous f32 from global, convert to bf16x8 fragment
__device__ __forceinline__ bf16x8 ldg8(const float* p) {
  const float4* q = (const float4*)p;
  float4 a = q[0];
  float4 b = q[1];
  u32x4 u;
  u.x = f2b_pk(a.x, a.y);
  u.y = f2b_pk(a.z, a.w);
  u.z = f2b_pk(b.x, b.y);
  u.w = f2b_pk(b.z, b.w);
  return __builtin_bit_cast(bf16x8, u);
}

// A-fragment (weights) from XOR-swizzled LDS image: row-major [M][K] bf16,
// swizzle byte ^= (row&7)<<4 (kills 16-way bank conflicts on 128/256B strides)
__device__ __forceinline__ bf16x8 ldsA(const char* smem, int baseByte, int row,
                                       int colElem, int strideElem) {
  int off = baseByte + (((row * strideElem + colElem) * 2) ^ ((row & 7) << 4));
  return __builtin_bit_cast(bf16x8, *(const u32x4*)(smem + off));
}

// LDS layout (bytes):
//   [    0,16384) wq^T [64][128]  (scale 0.25 folded in)
//   [16384,24576) wk^T [64][64]
//   [24576,32768) wv^T [64][64]
//   [32768,49152) wo^T [128][64]
//   [49152,57344) per-wave O buffers, 4 x [16][64] bf16
__global__ __launch_bounds__(256, 2)
void tpa_kernel(const float* __restrict__ t_, const float* __restrict__ z_,
                const float* __restrict__ mask_,
                const float* __restrict__ wq_, const float* __restrict__ wk_,
                const float* __restrict__ wv_, const float* __restrict__ wo_,
                const float* __restrict__ bo_, float* __restrict__ out_) {
  extern __shared__ char smem[];

  // ---- stage transposed+swizzled bf16 weights into LDS (once per block) ----
  for (int i = threadIdx.x; i < 24576; i += 256) {
    float v;
    int off;
    if (i < 8192) {                       // wq^T[r][cc] = wq[cc][r] * 0.25
      int r = i >> 7, cc = i & 127;
      v = wq_[cc * 64 + r] * 0.25f;
      off = 0 + ((i * 2) ^ ((r & 7) << 4));
    } else if (i < 12288) {               // wk^T
      int j = i - 8192, r = j >> 6, cc = j & 63;
      v = wk_[cc * 64 + r];
      off = 16384 + ((j * 2) ^ ((r & 7) << 4));
    } else if (i < 16384) {               // wv^T
      int j = i - 12288, r = j >> 6, cc = j & 63;
      v = wv_[cc * 64 + r];
      off = 24576 + ((j * 2) ^ ((r & 7) << 4));
    } else {                              // wo^T[r][cc] = wo[cc][r]
      int j = i - 16384, r = j >> 6, cc = j & 63;
      v = wo_[cc * 128 + r];
      off = 32768 + ((j * 2) ^ ((r & 7) << 4));
    }
    unsigned int u = __float_as_uint(v);
    *(unsigned short*)(smem + off) =
        (unsigned short)((u + 0x7fffu + ((u >> 16) & 1u)) >> 16);
  }
  __syncthreads();

  const int lane = threadIdx.x & 63;
  const int wid = threadIdx.x >> 6;
  const int c = lane & 15;  // pixel-within-tile (MFMA col), also A-frag row idx
  const int g = lane >> 4;  // k-chunk / d-group

  const float b0 = mask_[0] > 0.f ? 0.f : -1e9f;
  const float b1 = mask_[1] > 0.f ? 0.f : -1e9f;
  const float b2 = mask_[2] > 0.f ? 0.f : -1e9f;
  const float b3 = mask_[3] > 0.f ? 0.f : -1e9f;

  float4 bo_v[8];
#pragma unroll
  for (int m = 0; m < 8; ++m) bo_v[m] = *(const float4*)(bo_ + m * 16 + g * 4);

  char* Olds = smem + 49152 + wid * 2048;
  const f32x4 vz = {0.f, 0.f, 0.f, 0.f};

  // 9216 tiles of 16 pixels; 2048 waves (512 blocks x 4) -> 4-5 tiles/wave
  for (int tile = blockIdx.x * 4 + wid; tile < 9216; tile += 2048) {
    const int p = tile * 16 + c;
    const float* zp = z_ + (size_t)p * 128;
    const float* tp = t_ + (size_t)p * 64;

    // ---- Q^T = wq^T (A, LDS) * z^T (B, global): 4 K-steps x 4 head-tiles ----
    f32x4 qacc[4] = {vz, vz, vz, vz};
#pragma unroll
    for (int s = 0; s < 4; ++s) {
      bf16x8 zb = ldg8(zp + s * 32 + g * 8);
#pragma unroll
      for (int h = 0; h < 4; ++h)
        qacc[h] = MFMA16(ldsA(smem, 0, h * 16 + c, s * 32 + g * 8, 128), zb, qacc[h]);
    }

    // ---- per-template: K,V GEMMs share t fragments; un-shifted softmax ----
    f32x4 oacc[4] = {vz, vz, vz, vz};
    float ssum[4] = {0.f, 0.f, 0.f, 0.f};
#pragma unroll
    for (int tt = 0; tt < 4; ++tt) {
      const float* tq = tp + (size_t)tt * 9437184;  // tt * R*R*64
      bf16x8 tb0 = ldg8(tq + g * 8);
      bf16x8 tb1 = ldg8(tq + 32 + g * 8);
      f32x4 kacc[4] = {vz, vz, vz, vz};
      f32x4 vacc[4] = {vz, vz, vz, vz};
#pragma unroll
      for (int h = 0; h < 4; ++h) {
        kacc[h] = MFMA16(ldsA(smem, 16384, h * 16 + c, g * 8, 64), tb0, kacc[h]);
        kacc[h] = MFMA16(ldsA(smem, 16384, h * 16 + c, 32 + g * 8, 64), tb1, kacc[h]);
        vacc[h] = MFMA16(ldsA(smem, 24576, h * 16 + c, g * 8, 64), tb0, vacc[h]);
        vacc[h] = MFMA16(ldsA(smem, 24576, h * 16 + c, 32 + g * 8, 64), tb1, vacc[h]);
      }
      const float bt = (tt == 0) ? b0 : (tt == 1) ? b1 : (tt == 2) ? b2 : b3;
#pragma unroll
      for (int h = 0; h < 4; ++h) {
        // logit(p,h,tt): lane-local dot over its 4 d's, then sum the 4 g-groups
        float d = qacc[h][0] * kacc[h][0] + qacc[h][1] * kacc[h][1] +
                  qacc[h][2] * kacc[h][2] + qacc[h][3] * kacc[h][3];
        d += __shfl_xor(d, 16);
        d += __shfl_xor(d, 32);  // broadcast full dot to all 4 g-groups
        float e = __expf(d + bt);
        ssum[h] += e;
        oacc[h] += e * vacc[h];
      }
    }

    // ---- normalize, O -> LDS as bf16 (swizzled) ----
#pragma unroll
    for (int h = 0; h < 4; ++h) {
      float inv = 1.0f / ssum[h];
      f32x4 o = oacc[h] * inv;
      u32x2 w;
      w.x = f2b_pk(o[0], o[1]);
      w.y = f2b_pk(o[2], o[3]);
      int off = (c * 128 + h * 32 + g * 8) ^ ((c & 7) << 4);
      *(u32x2*)(Olds + off) = w;
    }
    asm volatile("s_waitcnt lgkmcnt(0)" ::: "memory");  // intra-wave LDS exchange

    // ---- OUT^T = wo^T (A, LDS) * O^T (B, LDS): 2 K-steps x 8 M-tiles ----
    f32x4 outacc[8] = {vz, vz, vz, vz, vz, vz, vz, vz};
#pragma unroll
    for (int s = 0; s < 2; ++s) {
      int off = (c * 128 + s * 64 + g * 16) ^ ((c & 7) << 4);
      bf16x8 ob = __builtin_bit_cast(bf16x8, *(const u32x4*)(Olds + off));
#pragma unroll
      for (int m = 0; m < 8; ++m)
        outacc[m] = MFMA16(ldsA(smem, 32768, m * 16 + c, s * 32 + g * 8, 64), ob, outacc[m]);
    }

    // ---- +bo, store: lane holds 4 consecutive out-feats -> float4 store ----
    float* op = out_ + (size_t)p * 128;
#pragma unroll
    for (int m = 0; m < 8; ++m) {
      float4 bv = bo_v[m];
      float4 st;
      st.x = outacc[m][0] + bv.x;
      st.y = outacc[m][1] + bv.y;
      st.z = outacc[m][2] + bv.z;
      st.w = outacc[m][3] + bv.w;
      *(float4*)(op + m * 16 + g * 4) = st;
    }
    asm volatile("" ::: "memory");  // keep next tile's LDS writes after this tile's reads
  }
}

extern "C" void kernel_launch(void* const* d_in, const int* in_sizes, int n_in,
                              void* d_out, int out_size, void* d_ws, size_t ws_size,
                              hipStream_t stream) {
  const float* t = (const float*)d_in[0];
  const float* z = (const float*)d_in[1];
  const float* mk = (const float*)d_in[2];
  const float* wq = (const float*)d_in[3];
  const float* wk = (const float*)d_in[4];
  const float* wv = (const float*)d_in[5];
  const float* wo = (const float*)d_in[6];
  const float* bo = (const float*)d_in[7];
  float* out = (float*)d_out;
  (void)in_sizes; (void)n_in; (void)out_size; (void)d_ws; (void)ws_size;

  hipLaunchKernelGGL(tpa_kernel, dim3(512), dim3(256), 57344, stream,
                     t, z, mk, wq, wk, wv, wo, bo, out);
}